// Round 8
// baseline (689.639 us; speedup 1.0000x reference)
//
#include <hip/hip_runtime.h>
#include <math.h>

#define DD 256
#define BB 1024
#define CC 64
#define VV 50000
#define TOPK 10
#define BM 128
#define BN 128
#define BK 64
#define LDK 72          // padded LDS row stride (bf16): 144 B rows, 16B-aligned; 2-way bank alias = free
#define NCHUNK 391      // ceil(VV/BN)
#define NMBLK 8         // BB/BM
#define NWG (NCHUNK * NMBLK)   // 3128 = 8 * 391 exactly
#define MAXCAND 60      // keeps base workspace (5,038,080 B) below the proven 5,050,368 B footprint
#define QLEN 12500      // VV/4: per-quarter span in k_scale (float4-aligned, chunk-aligned)

typedef __attribute__((ext_vector_type(8))) short bf16x8;
typedef __attribute__((ext_vector_type(4))) float f32x4;

__device__ inline unsigned short f2bf(float x) {
    unsigned u = __float_as_uint(x);
    unsigned r = (u + 0x7FFFu + ((u >> 16) & 1u)) >> 16;
    return (unsigned short)r;
}

// ---------------- Kernel 0: one-time CE fp32 -> bf16 (halves B fetch, removes per-tile f2bf) ----
__global__ __launch_bounds__(256) void k_prep(
    const float* __restrict__ CE, unsigned short* __restrict__ CEb)
{
    const int i = blockIdx.x * 256 + threadIdx.x;          // 8 elems per thread
    const size_t base = (size_t)i * 8;
    if (base >= (size_t)VV * DD) return;
    const float4 a = *(const float4*)(CE + base);
    const float4 b = *(const float4*)(CE + base + 4);
    uint4 o;
    o.x = (unsigned)f2bf(a.x) | ((unsigned)f2bf(a.y) << 16);
    o.y = (unsigned)f2bf(a.z) | ((unsigned)f2bf(a.w) << 16);
    o.z = (unsigned)f2bf(b.x) | ((unsigned)f2bf(b.y) << 16);
    o.w = (unsigned)f2bf(b.z) | ((unsigned)f2bf(b.w) << 16);
    *(uint4*)(CEb + base) = o;
}

// ---------------- Kernel 1 (fallback, proven): per-entity gather + attention + phrase ---------
__global__ __launch_bounds__(256) void k_phrase(
    const int* __restrict__ wl_ids, const int* __restrict__ wr_ids,
    const int* __restrict__ cl_ids, const int* __restrict__ cr_ids,
    const float* __restrict__ WE, const float* __restrict__ CE,
    const float* __restrict__ W_a, const float* __restrict__ b_a,
    const float* __restrict__ W_c, const float* __restrict__ b_c,
    float* __restrict__ phrase, unsigned short* __restrict__ phraseb)
{
    const int b = blockIdx.x;
    const int t = threadIdx.x;
    __shared__ float s_wl[DD], s_wr[DD], s_align[DD], s_agg0[DD], s_agg1[DD];
    __shared__ float s_part[256];
    __shared__ float s_att[CC];
    __shared__ int s_rid[CC];

    s_wl[t] = WE[(size_t)wl_ids[b] * DD + t];
    s_wr[t] = WE[(size_t)wr_ids[b] * DD + t];
    __syncthreads();

    for (int side = 0; side < 2; ++side) {
        const float* w    = (side == 0) ? s_wl : s_wr;
        const int*   cids = (side == 0) ? (cr_ids + b * CC) : (cl_ids + b * CC);

        float acc = b_a[t];
        #pragma unroll 4
        for (int k = 0; k < DD; ++k) acc = fmaf(w[k], W_a[k * DD + t], acc);
        s_align[t] = tanhf(acc);
        if (t < CC) s_rid[t] = cids[t];
        __syncthreads();

        {
            const int c = t & 63, p = t >> 6;
            const float* crow = CE + (size_t)s_rid[c] * DD + p * 64;
            const float* al = s_align + p * 64;
            float sc = 0.f;
            #pragma unroll 4
            for (int j = 0; j < 64; ++j) sc = fmaf(crow[j], al[j], sc);
            s_part[t] = sc;
        }
        __syncthreads();
        if (t < CC) {
            float s = s_part[t] + s_part[64 + t] + s_part[128 + t] + s_part[192 + t];
            float m = s;
            for (int off = 32; off; off >>= 1) m = fmaxf(m, __shfl_xor(m, off, 64));
            float e = expf(s - m);
            float sum = e;
            for (int off = 32; off; off >>= 1) sum += __shfl_xor(sum, off, 64);
            s_att[t] = e / sum;
        }
        __syncthreads();
        {
            float ag = 0.f;
            #pragma unroll 4
            for (int c = 0; c < CC; ++c)
                ag = fmaf(s_att[c], CE[(size_t)s_rid[c] * DD + t], ag);
            if (side == 0) s_agg0[t] = ag; else s_agg1[t] = ag;
        }
        __syncthreads();
    }

    s_wl[t]  += s_wr[t];
    s_agg0[t] += s_agg1[t];
    __syncthreads();

    float acc = b_c[t];
    #pragma unroll 4
    for (int k = 0; k < DD; ++k) acc = fmaf(s_wl[k],  W_c[k * DD + t], acc);
    #pragma unroll 4
    for (int k = 0; k < DD; ++k) acc = fmaf(s_agg0[k], W_c[(DD + k) * DD + t], acc);
    const float ph = tanhf(acc);
    phrase[b * DD + t] = ph;
    phraseb[b * DD + t] = f2bf(ph);
}

// ---------------- Kernel 1a: batched align GEMM  [2048,256] @ W_a, fused tanh --------------
__global__ __launch_bounds__(256) void k_align(
    const int* __restrict__ wl_ids, const int* __restrict__ wr_ids,
    const float* __restrict__ WE,
    const float* __restrict__ W_a, const float* __restrict__ b_a,
    float* __restrict__ alignbuf, float* __restrict__ wordsum)
{
    __shared__ float sA[32][260];     // 260 pad: float4 reads stay 16B-aligned (1040 = 65*16)
    __shared__ int s_id[32];

    const int t  = threadIdx.x;
    const int rt = blockIdx.x >> 2;   // row-tile [0,64)
    const int cg = blockIdx.x & 3;    // col-group [0,4)
    const int b0 = rt * 16;           // first entity
    const int s0 = rt * 32;           // first slot

    if (t < 32) {
        const int e = b0 + (t >> 1);
        s_id[t] = (t & 1) ? wr_ids[e] : wl_ids[e];
    }
    __syncthreads();

    #pragma unroll 8
    for (int r = 0; r < 32; ++r)
        sA[r][t] = WE[(size_t)s_id[r] * DD + t];
    __syncthreads();

    if (cg == 0) {
        #pragma unroll
        for (int i = 0; i < 16; ++i)
            wordsum[(size_t)(b0 + i) * DD + t] = sA[2 * i][t] + sA[2 * i + 1][t];
    }

    const int c = t & 63, mg = t >> 6;
    const int col = cg * 64 + c;
    const float ba = b_a[col];
    float acc[8];
    #pragma unroll
    for (int j = 0; j < 8; ++j) acc[j] = ba;

    for (int k4 = 0; k4 < 64; ++k4) {
        const int kb = k4 * 4;
        const float w0 = W_a[(size_t)(kb + 0) * DD + col];
        const float w1 = W_a[(size_t)(kb + 1) * DD + col];
        const float w2 = W_a[(size_t)(kb + 2) * DD + col];
        const float w3 = W_a[(size_t)(kb + 3) * DD + col];
        #pragma unroll
        for (int j = 0; j < 8; ++j) {
            const float4 a = *(const float4*)&sA[mg * 8 + j][kb];
            acc[j] = fmaf(a.x, w0, acc[j]);
            acc[j] = fmaf(a.y, w1, acc[j]);
            acc[j] = fmaf(a.z, w2, acc[j]);
            acc[j] = fmaf(a.w, w3, acc[j]);
        }
    }
    #pragma unroll
    for (int j = 0; j < 8; ++j)
        alignbuf[(size_t)(s0 + mg * 8 + j) * DD + col] = tanhf(acc[j]);
}

// ---------------- Kernel 1b: attention, one (entity, side) per block, NO CE staging ---------
// CE is L3-resident (51 MB); agg pass re-reads score-pass rows L1/L2-hot. LDS ~2.6 KB ->
// full occupancy (was 2 blocks/CU at 66.5 KB). The block's agg overwrites ITS OWN alignbuf
// row (each row consumed by exactly one block) — zero extra workspace.
__global__ __launch_bounds__(256) void k_attn(
    const int* __restrict__ cl_ids, const int* __restrict__ cr_ids,
    const float* __restrict__ CE, float* __restrict__ alignbuf)
{
    __shared__ float sAl[DD];
    __shared__ float s_part[256];
    __shared__ float s_att[CC];
    __shared__ int s_rid[CC];

    const int bid = blockIdx.x;
    const int b = bid >> 1, side = bid & 1;
    const int t = threadIdx.x;

    const int* cids = (side == 0) ? (cr_ids + b * CC) : (cl_ids + b * CC);
    if (t < CC) s_rid[t] = cids[t];
    sAl[t] = alignbuf[(size_t)(2 * b + side) * DD + t];
    __syncthreads();

    {   // scores: lane c walks 256B of its row (sequential float4), sAl from LDS
        const int c = t & 63, p = t >> 6;
        const float* crow = CE + (size_t)s_rid[c] * DD + p * 64;
        float sc = 0.f;
        #pragma unroll
        for (int jj = 0; jj < 16; ++jj) {
            const float4 v  = *(const float4*)(crow + 4 * jj);
            const float4 al = *(const float4*)&sAl[p * 64 + 4 * jj];
            sc = fmaf(v.x, al.x, sc);
            sc = fmaf(v.y, al.y, sc);
            sc = fmaf(v.z, al.z, sc);
            sc = fmaf(v.w, al.w, sc);
        }
        s_part[t] = sc;
    }
    __syncthreads();
    if (t < CC) {
        float s = s_part[t] + s_part[64 + t] + s_part[128 + t] + s_part[192 + t];
        float m = s;
        for (int off = 32; off; off >>= 1) m = fmaxf(m, __shfl_xor(m, off, 64));
        float e = expf(s - m);
        float sum = e;
        for (int off = 32; off; off >>= 1) sum += __shfl_xor(sum, off, 64);
        s_att[t] = e / sum;
    }
    __syncthreads();
    {   // agg: per c, 256 threads read one CE row coalesced (L2-hot from score pass)
        float ag = 0.f;
        #pragma unroll 8
        for (int c = 0; c < CC; ++c)
            ag = fmaf(s_att[c], CE[(size_t)s_rid[c] * DD + t], ag);
        alignbuf[(size_t)(2 * b + side) * DD + t] = ag;   // overwrite own row
    }
}

// ---------------- Kernel 1c: phrase GEMM  [1024,512] @ W_c, fused tanh + bf16 copy ----------
// Concat row = [wordsum | agg_l + agg_r] where aggs live in alignbuf rows 2b / 2b+1.
__global__ __launch_bounds__(256) void k_phrase2(
    const float* __restrict__ wordsum, const float* __restrict__ alignbuf,
    const float* __restrict__ W_c, const float* __restrict__ b_c,
    float* __restrict__ phrase, unsigned short* __restrict__ phraseb)
{
    __shared__ float sX[16][516];     // 516 pad: float4 16B-aligned (2064 = 129*16)

    const int t  = threadIdx.x;
    const int rt = blockIdx.x >> 2;
    const int cg = blockIdx.x & 3;
    const int b0 = rt * 16;

    #pragma unroll
    for (int i = 0; i < 16; ++i) {
        sX[i][t]      = wordsum[(size_t)(b0 + i) * DD + t];
        sX[i][DD + t] = alignbuf[(size_t)(2 * (b0 + i)) * DD + t]
                      + alignbuf[(size_t)(2 * (b0 + i) + 1) * DD + t];
    }
    __syncthreads();

    const int c = t & 63, mg = t >> 6;
    const int col = cg * 64 + c;
    const float bc = b_c[col];
    float acc[4];
    #pragma unroll
    for (int j = 0; j < 4; ++j) acc[j] = bc;

    for (int k4 = 0; k4 < 128; ++k4) {
        const int kb = k4 * 4;
        const float w0 = W_c[(size_t)(kb + 0) * DD + col];
        const float w1 = W_c[(size_t)(kb + 1) * DD + col];
        const float w2 = W_c[(size_t)(kb + 2) * DD + col];
        const float w3 = W_c[(size_t)(kb + 3) * DD + col];
        #pragma unroll
        for (int j = 0; j < 4; ++j) {
            const float4 a = *(const float4*)&sX[mg * 4 + j][kb];
            acc[j] = fmaf(a.x, w0, acc[j]);
            acc[j] = fmaf(a.y, w1, acc[j]);
            acc[j] = fmaf(a.z, w2, acc[j]);
            acc[j] = fmaf(a.w, w3, acc[j]);
        }
    }
    #pragma unroll
    for (int j = 0; j < 4; ++j) {
        const int b = b0 + mg * 4 + j;
        const float ph = tanhf(acc[j]);
        phrase[(size_t)b * DD + col] = ph;
        phraseb[(size_t)b * DD + col] = f2bf(ph);
    }
}

// ---------------- Kernel 2: SINGLE bf16 MFMA GEMM pass ----------------
// Computes per-chunk {max, sumexp} AND stores u = exp(x - m_chunk) into out (staged,
// coalesced). Normalization to y = u * exp(m_chunk - M) * invS is a scalar per
// (row, chunk) applied by the streaming k_scale pass — the second GEMM is eliminated.
template<bool BF16CE>
__global__ __launch_bounds__(256) void k_gemm(
    const unsigned short* __restrict__ phraseb,
    const float* __restrict__ CE, const unsigned short* __restrict__ CEb,
    float* __restrict__ out,
    float* __restrict__ pmax, float* __restrict__ psum)
{
    __shared__ __align__(16) char smem_raw[BM * LDK * 2 * 2];   // sA | sB (36,864 B)
    __shared__ float sM[2][BM], sS[2][BM];
    unsigned short* sA = (unsigned short*)smem_raw;
    unsigned short* sB = sA + BM * LDK;

    const int t = threadIdx.x;
    const int wave = t >> 6, lane = t & 63;
    const int wm = wave >> 1, wn = wave & 1;
    const int quad = lane >> 4, l15 = lane & 15;

    const int wg = blockIdx.x;
    const int q  = (wg & 7) * NCHUNK + (wg >> 3);   // XCD-bijective: 3128 = 8*391
    const int m0 = (q & 7) * BM;
    const int cn = q >> 3;
    const int n0 = cn * BN;

    f32x4 acc[4][4] = {};

    for (int k0 = 0; k0 < DD; k0 += BK) {
        __syncthreads();
        #pragma unroll
        for (int r = 0; r < 4; ++r) {
            const int idx = t + r * 256;
            const int m = idx >> 3, k8 = (idx & 7) * 8;
            const uint4 v = *(const uint4*)(phraseb + (size_t)(m0 + m) * DD + k0 + k8);
            *(uint4*)(sA + m * LDK + k8) = v;
        }
        if constexpr (BF16CE) {
            #pragma unroll
            for (int r = 0; r < 4; ++r) {
                const int idx = t + r * 256;
                const int n = idx >> 3, k8 = (idx & 7) * 8;
                const int gn = n0 + n;
                uint4 v = make_uint4(0u, 0u, 0u, 0u);
                if (gn < VV) v = *(const uint4*)(CEb + (size_t)gn * DD + k0 + k8);
                *(uint4*)(sB + n * LDK + k8) = v;
            }
        } else {
            #pragma unroll
            for (int r = 0; r < 8; ++r) {
                const int idx = t + r * 256;
                const int n = idx >> 4, k4 = (idx & 15) * 4;
                const int gn = n0 + n;
                float4 v = make_float4(0.f, 0.f, 0.f, 0.f);
                if (gn < VV) v = *(const float4*)(CE + (size_t)gn * DD + k0 + k4);
                ushort4 h;
                h.x = f2bf(v.x); h.y = f2bf(v.y); h.z = f2bf(v.z); h.w = f2bf(v.w);
                *(ushort4*)(sB + n * LDK + k4) = h;
            }
        }
        __syncthreads();
        #pragma unroll
        for (int kk = 0; kk < BK; kk += 32) {
            bf16x8 af[4], bfr[4];
            #pragma unroll
            for (int i = 0; i < 4; ++i) {
                af[i]  = *(const bf16x8*)(sA + (wm * 64 + i * 16 + l15) * LDK + kk + quad * 8);
                bfr[i] = *(const bf16x8*)(sB + (wn * 64 + i * 16 + l15) * LDK + kk + quad * 8);
            }
            #pragma unroll
            for (int i = 0; i < 4; ++i)
                #pragma unroll
                for (int j = 0; j < 4; ++j)
                    acc[i][j] = __builtin_amdgcn_mfma_f32_16x16x32_bf16(af[i], bfr[j], acc[i][j], 0, 0, 0);
        }
    }

    bool val[4];
    #pragma unroll
    for (int j = 0; j < 4; ++j) val[j] = (n0 + wn * 64 + j * 16 + l15) < VV;

    // ---- per-half chunk stats ----
    #pragma unroll
    for (int i = 0; i < 4; ++i) {
        #pragma unroll
        for (int r = 0; r < 4; ++r) {
            float m1 = -INFINITY;
            #pragma unroll
            for (int j = 0; j < 4; ++j) if (val[j]) m1 = fmaxf(m1, acc[i][j][r]);
            #pragma unroll
            for (int off = 8; off >= 1; off >>= 1) m1 = fmaxf(m1, __shfl_xor(m1, off, 64));
            float s = 0.f;
            #pragma unroll
            for (int j = 0; j < 4; ++j) if (val[j]) s += __expf(acc[i][j][r] - m1);
            #pragma unroll
            for (int off = 8; off >= 1; off >>= 1) s += __shfl_xor(s, off, 64);
            if (l15 == 0) {
                const int mloc = wm * 64 + i * 16 + quad * 4 + r;
                sM[wn][mloc] = m1;
                sS[wn][mloc] = s;
            }
        }
    }
    __syncthreads();
    if (t < BM) {   // combine halves -> chunk stats; keep combined max in sM[0]
        const float Ma = sM[0][t], Mb = sM[1][t];
        const float nM = fmaxf(Ma, Mb);
        const float S  = sS[0][t] * __expf(Ma - nM) + sS[1][t] * __expf(Mb - nM);
        const size_t o = (size_t)(m0 + t) * NCHUNK + cn;
        pmax[o] = nM;
        psum[o] = S;
        sM[0][t] = nM;
    }

    // ---- staged coalesced u-store (u = exp(x - m_chunk)) ----
    float* stage = (float*)smem_raw;      // 32 rows x 132 f32 = 16,896 B
    #pragma unroll
    for (int h = 0; h < 4; ++h) {
        __syncthreads();                  // h=0: also publishes sM[0] + frees sA/sB
        if (wm == (h >> 1)) {
            const int ibase = (h & 1) * 2;
            #pragma unroll
            for (int ii = 0; ii < 2; ++ii) {
                const int i = ibase + ii;
                #pragma unroll
                for (int r = 0; r < 4; ++r) {
                    const int ml = wm * 64 + i * 16 + quad * 4 + r;
                    const int rl = ii * 16 + quad * 4 + r;            // [0,32)
                    const float mc = sM[0][ml];
                    #pragma unroll
                    for (int j = 0; j < 4; ++j)
                        stage[rl * 132 + wn * 64 + j * 16 + l15] = __expf(acc[i][j][r] - mc);
                }
            }
        }
        __syncthreads();
        #pragma unroll
        for (int k = 0; k < 4; ++k) {
            const int f = t + k * 256;
            const int row = f >> 5, c4 = f & 31;
            const int gcol = n0 + c4 * 4;
            if (gcol + 3 < VV) {          // VV - 390*BN = 80 ≡ 0 mod 4: no partial float4
                const f32x4 v = *(const f32x4*)&stage[row * 132 + c4 * 4];
                __builtin_nontemporal_store(v,
                    (f32x4*)(out + (size_t)(m0 + h * 32 + row) * VV + gcol));
            }
        }
    }
}

// ---------------- Kernel 3: merge per-chunk stats -> rowM, invS, threshold ----------------
__global__ __launch_bounds__(64) void k_rowstats(
    const float* __restrict__ pmax, const float* __restrict__ psum,
    float* __restrict__ rowM, float* __restrict__ rowInvS, float* __restrict__ rowTh,
    int* __restrict__ cand_cnt)
{
    const int b = blockIdx.x, t = threadIdx.x;
    float M = -INFINITY, S = 0.f;
    float top[TOPK];
    #pragma unroll
    for (int j = 0; j < TOPK; ++j) top[j] = -INFINITY;

    for (int c = t; c < NCHUNK; c += 64) {
        const float m = pmax[(size_t)b * NCHUNK + c];
        const float s = psum[(size_t)b * NCHUNK + c];
        const float nM = fmaxf(M, m);
        S = S * __expf(M - nM) + s * __expf(m - nM);
        M = nM;
        if (m > top[TOPK - 1]) {
            float v = m;
            #pragma unroll
            for (int p = 0; p < TOPK; ++p) {
                const float hi = fmaxf(top[p], v), lo = fminf(top[p], v);
                top[p] = hi; v = lo;
            }
        }
    }
    #pragma unroll
    for (int off = 32; off; off >>= 1) {
        const float m2 = __shfl_xor(M, off, 64);
        const float s2 = __shfl_xor(S, off, 64);
        const float nM = fmaxf(M, m2);
        S = S * __expf(M - nM) + s2 * __expf(m2 - nM);
        M = nM;
    }
    float v10 = -INFINITY;
    for (int k = 0; k < TOPK; ++k) {
        float g = top[0];
        #pragma unroll
        for (int off = 32; off; off >>= 1) g = fmaxf(g, __shfl_xor(g, off, 64));
        v10 = g;
        const unsigned long long mk = __ballot(top[0] == g);
        if (mk && t == __ffsll(mk) - 1) {
            #pragma unroll
            for (int p = 0; p < TOPK - 1; ++p) top[p] = top[p + 1];
            top[TOPK - 1] = -INFINITY;
        }
    }
    if (t == 0) {
        rowM[b] = M;
        const float inv = 1.f / S;
        rowInvS[b] = inv;
        rowTh[b] = 0.90f * __expf(v10 - M) * inv;
        cand_cnt[b] = 0;
    }
}

// ---------------- Kernel 4: streaming scale  y = u * f[chunk], fused candidate emit --------
// f[c] = exp(m_chunk - M) * invS staged in LDS (391 floats). Pure-BW in-place pass.
__global__ __launch_bounds__(256) void k_scale(
    float* __restrict__ ylog, const float* __restrict__ pmax,
    const float* __restrict__ rowM, const float* __restrict__ rowInvS,
    const float* __restrict__ rowTh,
    int* __restrict__ cand_idx, int* __restrict__ cand_cnt)
{
    __shared__ float f[NCHUNK];
    const int b = blockIdx.x, qq = blockIdx.y, t = threadIdx.x;
    const float M = rowM[b];
    const float inv = rowInvS[b];
    const float th = rowTh[b];
    for (int c = t; c < NCHUNK; c += 256)
        f[c] = __expf(pmax[(size_t)b * NCHUNK + c] - M) * inv;
    __syncthreads();

    float* row = ylog + (size_t)b * VV;
    const int end = (qq + 1) * QLEN;
    for (int i = qq * QLEN + t * 4; i < end; i += 1024) {
        const f32x4 u = *(const f32x4*)(row + i);
        const float fc = f[i >> 7];          // i..i+3 share a 128-col chunk (i is 4-aligned)
        const f32x4 y = u * fc;
        __builtin_nontemporal_store(y, (f32x4*)(row + i));
        #pragma unroll
        for (int jj = 0; jj < 4; ++jj) {
            if (y[jj] >= th) {
                const int p = atomicAdd(&cand_cnt[b], 1);
                if (p < MAXCAND) cand_idx[b * MAXCAND + p] = i + jj;
            }
        }
    }
}

// ---------------- Kernel 5: exact fp32 rescore of candidates -> final indices ----------------
__global__ __launch_bounds__(64) void k_rescore(
    const float* __restrict__ phrase, const float* __restrict__ CE,
    const int* __restrict__ cand_idx, const int* __restrict__ cand_cnt,
    float* __restrict__ topk_out)
{
    const int b = blockIdx.x, lane = threadIdx.x;
    int cnt = cand_cnt[b];
    if (cnt > MAXCAND) cnt = MAXCAND;
    __shared__ float s_val[MAXCAND];
    __shared__ int   s_idx[MAXCAND];

    if (lane < MAXCAND) { s_val[lane] = -INFINITY; s_idx[lane] = 0x7ffffff0; }
    __syncthreads();

    const float4 ph = *(const float4*)(phrase + (size_t)b * DD + lane * 4);
    for (int c = 0; c < cnt; ++c) {
        const int id = cand_idx[b * MAXCAND + c];
        const float4 ce = *(const float4*)(CE + (size_t)id * DD + lane * 4);
        float d = ph.x * ce.x + ph.y * ce.y + ph.z * ce.z + ph.w * ce.w;
        #pragma unroll
        for (int off = 32; off; off >>= 1) d += __shfl_xor(d, off, 64);
        if (lane == 0) { s_val[c] = d; s_idx[c] = id; }
    }
    __syncthreads();
    if (lane == 0) {
        for (int j = 0; j < TOPK; ++j) {
            int best = j;
            for (int c = j + 1; c < cnt; ++c) {
                if (s_val[c] > s_val[best] ||
                    (s_val[c] == s_val[best] && s_idx[c] < s_idx[best])) best = c;
            }
            const float bv = s_val[best]; const int bi = s_idx[best];
            s_val[best] = s_val[j]; s_idx[best] = s_idx[j];
            s_val[j] = bv; s_idx[j] = bi;
            topk_out[b * TOPK + j] = (float)bi;
        }
    }
}

extern "C" void kernel_launch(void* const* d_in, const int* in_sizes, int n_in,
                              void* d_out, int out_size, void* d_ws, size_t ws_size,
                              hipStream_t stream) {
    const int*   wl_ids = (const int*)d_in[0];
    const int*   wr_ids = (const int*)d_in[1];
    const int*   cl_ids = (const int*)d_in[2];
    const int*   cr_ids = (const int*)d_in[3];
    const float* WE     = (const float*)d_in[4];
    const float* CE     = (const float*)d_in[5];
    const float* W_a    = (const float*)d_in[6];
    const float* b_a    = (const float*)d_in[7];
    const float* W_c    = (const float*)d_in[8];
    const float* b_c    = (const float*)d_in[9];

    float* out = (float*)d_out;
    float* ws  = (float*)d_ws;

    // Base layout: 5,038,080 B — within the 5,050,368 B footprint proven by prior sessions.
    float* phrase  = ws;                                        // 262144 f
    unsigned short* phraseb = (unsigned short*)(ws + 262144);   // 131072 f
    float* pmax    = ws + 262144 + 131072;                      // 400384 f
    float* psum    = pmax + (size_t)BB * NCHUNK;                // 400384 f
    float* rowM    = psum + (size_t)BB * NCHUNK;                // 1024 f
    float* rowInvS = rowM + BB;                                 // 1024 f
    float* rowTh   = rowInvS + BB;                              // 1024 f
    int*   cand_idx = (int*)(rowTh + BB);                       // BB*60 i
    int*   cand_cnt = cand_idx + (size_t)BB * MAXCAND;          // 1024 i
    float* topk_out = out + (size_t)BB * VV;

    const size_t baseBytes = (size_t)((char*)(cand_cnt + BB) - (char*)ws);

    // ext1 (phrase pipeline): alignbuf 2 MB (align -> agg in place) + wordsum 1 MB
    float* alignbuf = (float*)((char*)ws + baseBytes);          // 2048*256 f
    float* wordsum  = alignbuf + (size_t)2 * BB * DD;           // 1024*256 f
    const size_t ext1End = baseBytes + (size_t)3 * BB * DD * 4; // +3,145,728 B
    const bool newphrase = ws_size >= ext1End;

    const size_t ceOff = ((newphrase ? ext1End : baseBytes) + 255) & ~(size_t)255;
    const bool bf16ce = ws_size >= ceOff + (size_t)VV * DD * 2;  // +25.6 MB, runtime-gated
    unsigned short* CEb = (unsigned short*)((char*)ws + ceOff);

    if (newphrase) {
        k_align<<<256, 256, 0, stream>>>(wl_ids, wr_ids, WE, W_a, b_a, alignbuf, wordsum);
        k_attn<<<2 * BB, 256, 0, stream>>>(cl_ids, cr_ids, CE, alignbuf);
        k_phrase2<<<256, 256, 0, stream>>>(wordsum, alignbuf, W_c, b_c, phrase, phraseb);
    } else {
        k_phrase<<<BB, 256, 0, stream>>>(wl_ids, wr_ids, cl_ids, cr_ids,
                                         WE, CE, W_a, b_a, W_c, b_c, phrase, phraseb);
    }
    if (bf16ce) {
        k_prep<<<(VV * DD / 8 + 255) / 256, 256, 0, stream>>>(CE, CEb);
        k_gemm<true><<<NWG, 256, 0, stream>>>(phraseb, CE, CEb, out, pmax, psum);
    } else {
        k_gemm<false><<<NWG, 256, 0, stream>>>(phraseb, CE, CEb, out, pmax, psum);
    }
    k_rowstats<<<BB, 64, 0, stream>>>(pmax, psum, rowM, rowInvS, rowTh, cand_cnt);
    k_scale<<<dim3(BB, 4), 256, 0, stream>>>(out, pmax, rowM, rowInvS, rowTh,
                                             cand_idx, cand_cnt);
    k_rescore<<<BB, 64, 0, stream>>>(phrase, CE, cand_idx, cand_cnt, topk_out);
}